// Round 6
// baseline (642.488 us; speedup 1.0000x reference)
//
#include <hip/hip_runtime.h>
#include <hip/hip_bf16.h>
#include <cstdint>

// GCN: 2-layer GraphConv + dense head on MI355X. Round 6 (= round-5 fix):
//  - prep1 cast segment: grid-strided persistent blocks, 16 floats/thread/iter,
//    non-temporal fp32 reads via native clang vector type (uint4 rejected)
//  - otherwise round-4 structure: merged prep, fused dual GEMM, fused tail

static constexpr int N0 = 100000;
static constexpr int N1 = 20000;
static constexpr int N2 = 4000;
static constexpr int HH = 512;
static constexpr int C  = 10;
static constexpr int M1PAD = 20096;  // 157 * 128
static constexpr int CAST_BLOCKS = 1536;

using frag  = __attribute__((ext_vector_type(8))) short;
using f32x4 = __attribute__((ext_vector_type(4))) float;
using u32x4 = __attribute__((ext_vector_type(4))) unsigned int;  // native vec for nontemporal builtins

__device__ inline float bf2f(unsigned short u) {
    unsigned t = ((unsigned)u) << 16; float f; __builtin_memcpy(&f, &t, 4); return f;
}
__device__ inline unsigned short f2bf(float f) {
    unsigned u; __builtin_memcpy(&u, &f, 4);
    u += 0x7FFFu + ((u >> 16) & 1u);  // RNE
    return (unsigned short)(u >> 16);
}
__device__ inline unsigned short f2bf_u32(unsigned u) {
    u += 0x7FFFu + ((u >> 16) & 1u);  // RNE on raw fp32 bits
    return (unsigned short)(u >> 16);
}
__device__ inline void gld16(const void* g, void* l) {
    __builtin_amdgcn_global_load_lds((const __attribute__((address_space(1))) void*)g,
                                     (__attribute__((address_space(3))) void*)l,
                                     16, 0, 0);
}

// ---------------- prep1: edge-count atomics + x cast + weight cast + P1 -----
__global__ __launch_bounds__(256)
void prep1_k(const int* __restrict__ dst1, const int* __restrict__ dst2,
             int* __restrict__ cnt1, int* __restrict__ cnt2, int E1, int E2,
             const float* __restrict__ x, unsigned short* __restrict__ xb,
             const float* __restrict__ Wrel1, const float* __restrict__ Wroot1,
             unsigned short* __restrict__ Wt,
             const float* __restrict__ Wlin, const float* __restrict__ Whead,
             float* __restrict__ P1,
             int nbCount) {
    __shared__ float tsh[32][33];
    int b = blockIdx.x;
    if (b < nbCount) {                       // ---- edge counting (atomics) ----
        int g = b * 256 + threadIdx.x;
        if (g < E1) atomicAdd(&cnt1[dst1[g]], 1);
        else if (g < E1 + E2) atomicAdd(&cnt2[dst2[g - E1]], 1);
        return;
    }
    b -= nbCount;
    if (b < CAST_BLOCKS) {                   // ---- x -> bf16, grid-strided ----
        const int n16 = N0 * HH / 16;        // 3.2M iters of 16 floats
        const int stride = CAST_BLOCKS * 256;
        for (int g = b * 256 + (int)threadIdx.x; g < n16; g += stride) {
            const u32x4* p = (const u32x4*)x + (size_t)g * 4;
            u32x4 a  = __builtin_nontemporal_load(p);
            u32x4 b4 = __builtin_nontemporal_load(p + 1);
            u32x4 c4 = __builtin_nontemporal_load(p + 2);
            u32x4 d4 = __builtin_nontemporal_load(p + 3);
            unsigned short t[16] = {
                f2bf_u32(a[0]),  f2bf_u32(a[1]),  f2bf_u32(a[2]),  f2bf_u32(a[3]),
                f2bf_u32(b4[0]), f2bf_u32(b4[1]), f2bf_u32(b4[2]), f2bf_u32(b4[3]),
                f2bf_u32(c4[0]), f2bf_u32(c4[1]), f2bf_u32(c4[2]), f2bf_u32(c4[3]),
                f2bf_u32(d4[0]), f2bf_u32(d4[1]), f2bf_u32(d4[2]), f2bf_u32(d4[3])};
            u32x4* o = (u32x4*)(xb + (size_t)g * 16);
            o[0] = ((const u32x4*)t)[0];
            o[1] = ((const u32x4*)t)[1];
        }
        return;
    }
    b -= CAST_BLOCKS;
    if (b < 512) {                           // ---- weight transpose+cast ----
        int z = b >> 8, rem = b & 255;
        int bx = (rem & 15) * 32, by = (rem >> 4) * 32;
        const float* W = z ? Wroot1 : Wrel1;
        unsigned short* O = Wt + (size_t)z * HH * HH;
        int tx = threadIdx.x & 31, ty = threadIdx.x >> 5;
#pragma unroll
        for (int i = 0; i < 4; ++i)
            tsh[ty + i * 8][tx] = W[(size_t)(by + ty + i * 8) * HH + bx + tx];
        __syncthreads();
#pragma unroll
        for (int i = 0; i < 4; ++i)
            O[(size_t)(bx + ty + i * 8) * HH + by + tx] = f2bf(tsh[tx][ty + i * 8]);
        return;
    }
    b -= 512;
    {                                        // ---- P1 = Wlin @ Whead ----
        int g = b * 256 + threadIdx.x;
        if (g < HH * C) {
            int k = g / C, c = g % C;
            float acc = 0.f;
            const float* row = Wlin + (size_t)k * HH;
#pragma unroll 4
            for (int j = 0; j < HH; ++j) acc += row[j] * Whead[j * C + c];
            P1[g] = acc;
        }
    }
}

// ---------------- prep2: two exscans + W2aT/W2bT + bout ----------------
__global__ __launch_bounds__(1024)
void prep2_k(const int* __restrict__ cnt1, int* __restrict__ rs1,
             const int* __restrict__ cnt2, int* __restrict__ rs2,
             const float* __restrict__ Wrel2, const float* __restrict__ Wroot2,
             const float* __restrict__ P1,
             const float* __restrict__ brel2, const float* __restrict__ blin,
             const float* __restrict__ Whead, const float* __restrict__ bhead,
             float* __restrict__ W2aT, float* __restrict__ W2bT,
             float* __restrict__ bout) {
    __shared__ int part[1024];
    int blk = blockIdx.x;
    int t = threadIdx.x;
    if (blk < 2) {                           // ---- exclusive scans ----
        const int* cnt = blk ? cnt2 : cnt1;
        int* rs = blk ? rs2 : rs1;
        int n = blk ? N2 : N1;
        int chunk = (n + 1023) >> 10;
        int bb = t * chunk;
        int e = min(bb + chunk, n);
        int s = 0;
        for (int i = bb; i < e; ++i) s += cnt[i];
        part[t] = s;
        __syncthreads();
        for (int off = 1; off < 1024; off <<= 1) {
            int add = (t >= off) ? part[t - off] : 0;
            __syncthreads();
            part[t] += add;
            __syncthreads();
        }
        int base = (t == 0) ? 0 : part[t - 1];
        for (int i = bb; i < e; ++i) { rs[i] = base; base += cnt[i]; }
        if (t == 1023) rs[n] = part[1023];
        return;
    }
    if (blk < 12) {                          // ---- W2aT / W2bT ----
        int z = (blk - 2) >= 5;
        int g = (blk - 2 - z * 5) * 1024 + t;
        if (g < HH * C) {
            const float* W = z ? Wroot2 : Wrel2;
            float* O = z ? W2bT : W2aT;
            int k = g / C, c = g % C;
            float acc = 0.f;
            const float* row = W + (size_t)k * HH;
#pragma unroll 4
            for (int j = 0; j < HH; ++j) acc += row[j] * P1[j * C + c];
            O[c * HH + k] = acc;             // transposed [10][512]
        }
        return;
    }
    if (t < C) {                             // ---- bout ----
        float acc = bhead[t];
        for (int j = 0; j < HH; ++j)
            acc += brel2[j] * P1[j * C + t] + blin[j] * Whead[j * C + t];
        bout[t] = acc;
    }
}

// ---------------- CSR fill (both layers) ----------------
__global__ void fill_both_k(const int* __restrict__ src1, const int* __restrict__ dst1,
                            const int* __restrict__ src2, const int* __restrict__ dst2,
                            const int* __restrict__ rs1, const int* __restrict__ rs2,
                            int* __restrict__ cur1, int* __restrict__ cur2,
                            int* __restrict__ eidx1, int* __restrict__ eidx2,
                            int E1, int E2) {
    int g = blockIdx.x * 256 + threadIdx.x;
    if (g < E1) {
        int d = dst1[g];
        int pos = atomicAdd(&cur1[d], 1);
        eidx1[rs1[d] + pos] = src1[g];
    } else if (g < E1 + E2) {
        int gg = g - E1;
        int d = dst2[gg];
        int pos = atomicAdd(&cur2[d], 1);
        eidx2[rs2[d] + pos] = src2[gg];
    }
}

// ---------------- aggregation: one wave per node, 8-edge unroll ----------------
__global__ __launch_bounds__(256)
void agg_bf16_k(const unsigned short* __restrict__ x, const int* __restrict__ rs,
                const int* __restrict__ eidx, unsigned short* __restrict__ out, int n) {
    int node = blockIdx.x * 4 + (threadIdx.x >> 6);
    if (node >= n) return;
    int l = threadIdx.x & 63;
    int s = rs[node], e = rs[node + 1];
    float acc[8] = {};
    int i = s;
    for (; i + 8 <= e; i += 8) {
        uint4 v[8];
#pragma unroll
        for (int u = 0; u < 8; ++u)
            v[u] = *(const uint4*)(x + (size_t)eidx[i + u] * HH + l * 8);
#pragma unroll
        for (int u = 0; u < 8; ++u) {
            const unsigned short* pv = (const unsigned short*)&v[u];
#pragma unroll
            for (int j = 0; j < 8; ++j) acc[j] += bf2f(pv[j]);
        }
    }
    for (; i < e; ++i) {
        uint4 a = *(const uint4*)(x + (size_t)eidx[i] * HH + l * 8);
        const unsigned short* pa = (const unsigned short*)&a;
#pragma unroll
        for (int j = 0; j < 8; ++j) acc[j] += bf2f(pa[j]);
    }
    unsigned short o[8];
#pragma unroll
    for (int j = 0; j < 8; ++j) o[j] = f2bf(acc[j]);
    *(uint4*)(out + (size_t)node * HH + l * 8) = *(const uint4*)o;
}

// ---------------- bf16 MFMA GEMM (layer 1, dual fused in k-loop) ----------------
__global__ __launch_bounds__(256)
void gemm_mfma_k(const short* __restrict__ A1, const short* __restrict__ B1t,
                 const short* __restrict__ A2, const short* __restrict__ B2t,
                 const float* __restrict__ bias, unsigned short* __restrict__ Cout,
                 int M) {
    __shared__ __align__(16) short Ls[4 * 128 * 32];   // A1 | A2 | B1 | B2 (32 KB)
    short* As1 = Ls;
    short* As2 = Ls + 4096;
    short* Bs1 = Ls + 8192;
    short* Bs2 = Ls + 12288;
    const int bn = blockIdx.x * 128;
    const int bm = blockIdx.y * 128;
    const int tid = threadIdx.x;
    const int lane = tid & 63;
    const int wave = tid >> 6;
    const int l15 = lane & 15;
    const int quad = lane >> 4;
    const int wm = (wave >> 1) * 64;
    const int wn = (wave & 1) * 64;
    const int r0 = tid >> 2;
    const int sg = (tid & 3) * 8;

    f32x4 acc[4][4] = {};

    for (int k0 = 0; k0 < 512; k0 += 32) {
        gld16(A1 + (size_t)(bm + r0) * 512 + k0 + sg,        As1 + tid * 8);
        gld16(A1 + (size_t)(bm + r0 + 64) * 512 + k0 + sg,   As1 + (tid + 256) * 8);
        gld16(A2 + (size_t)(bm + r0) * 512 + k0 + sg,        As2 + tid * 8);
        gld16(A2 + (size_t)(bm + r0 + 64) * 512 + k0 + sg,   As2 + (tid + 256) * 8);
        gld16(B1t + (size_t)(bn + r0) * 512 + k0 + sg,       Bs1 + tid * 8);
        gld16(B1t + (size_t)(bn + r0 + 64) * 512 + k0 + sg,  Bs1 + (tid + 256) * 8);
        gld16(B2t + (size_t)(bn + r0) * 512 + k0 + sg,       Bs2 + tid * 8);
        gld16(B2t + (size_t)(bn + r0 + 64) * 512 + k0 + sg,  Bs2 + (tid + 256) * 8);
        __syncthreads();
        {
            frag a[4], b[4];
#pragma unroll
            for (int mi = 0; mi < 4; ++mi)
                a[mi] = *(const frag*)(As1 + (wm + mi * 16 + l15) * 32 + quad * 8);
#pragma unroll
            for (int ni = 0; ni < 4; ++ni)
                b[ni] = *(const frag*)(Bs1 + (wn + ni * 16 + l15) * 32 + quad * 8);
#pragma unroll
            for (int mi = 0; mi < 4; ++mi)
#pragma unroll
                for (int ni = 0; ni < 4; ++ni)
                    acc[mi][ni] = __builtin_amdgcn_mfma_f32_16x16x32_bf16(
                        a[mi], b[ni], acc[mi][ni], 0, 0, 0);
#pragma unroll
            for (int mi = 0; mi < 4; ++mi)
                a[mi] = *(const frag*)(As2 + (wm + mi * 16 + l15) * 32 + quad * 8);
#pragma unroll
            for (int ni = 0; ni < 4; ++ni)
                b[ni] = *(const frag*)(Bs2 + (wn + ni * 16 + l15) * 32 + quad * 8);
#pragma unroll
            for (int mi = 0; mi < 4; ++mi)
#pragma unroll
                for (int ni = 0; ni < 4; ++ni)
                    acc[mi][ni] = __builtin_amdgcn_mfma_f32_16x16x32_bf16(
                        a[mi], b[ni], acc[mi][ni], 0, 0, 0);
        }
        __syncthreads();
    }

#pragma unroll
    for (int ni = 0; ni < 4; ++ni) {
        const int gn = bn + wn + ni * 16 + l15;
        const float bv = bias[gn];
#pragma unroll
        for (int mi = 0; mi < 4; ++mi) {
            const int gm0 = bm + wm + mi * 16 + quad * 4;
#pragma unroll
            for (int r = 0; r < 4; ++r) {
                const int gm = gm0 + r;
                if (gm < M) {
                    float v = fmaxf(acc[mi][ni][r] + bv, 0.f);
                    Cout[(size_t)gm * 512 + gn] = f2bf(v);
                }
            }
        }
    }
}

// ---------------- fused tail: gather + [512,10] matvec -> out ----------------
__global__ __launch_bounds__(256)
void tail_k(const unsigned short* __restrict__ h, const int* __restrict__ rs,
            const int* __restrict__ eidx,
            const float* __restrict__ W2aT, const float* __restrict__ W2bT,
            const float* __restrict__ bout, float* __restrict__ out) {
    int node = blockIdx.x * 4 + (threadIdx.x >> 6);
    if (node >= N2) return;
    int l = threadIdx.x & 63;
    int s = rs[node], e = rs[node + 1];
    float acc[8] = {};
    int i = s;
    for (; i + 4 <= e; i += 4) {
        uint4 v[4];
#pragma unroll
        for (int u = 0; u < 4; ++u)
            v[u] = *(const uint4*)(h + (size_t)eidx[i + u] * HH + l * 8);
#pragma unroll
        for (int u = 0; u < 4; ++u) {
            const unsigned short* pv = (const unsigned short*)&v[u];
#pragma unroll
            for (int j = 0; j < 8; ++j) acc[j] += bf2f(pv[j]);
        }
    }
    for (; i < e; ++i) {
        uint4 a = *(const uint4*)(h + (size_t)eidx[i] * HH + l * 8);
        const unsigned short* pa = (const unsigned short*)&a;
#pragma unroll
        for (int j = 0; j < 8; ++j) acc[j] += bf2f(pa[j]);
    }
    float r[8];
    {
        uint4 a = *(const uint4*)(h + (size_t)node * HH + l * 8);
        const unsigned short* pa = (const unsigned short*)&a;
#pragma unroll
        for (int j = 0; j < 8; ++j) r[j] = bf2f(pa[j]);
    }
    float p[C];
#pragma unroll
    for (int c = 0; c < C; ++c) {
        const float* wa = W2aT + c * HH + l * 8;
        const float* wb = W2bT + c * HH + l * 8;
        float4 wa0 = *(const float4*)wa, wa1 = *(const float4*)(wa + 4);
        float4 wb0 = *(const float4*)wb, wb1 = *(const float4*)(wb + 4);
        float v = acc[0] * wa0.x + acc[1] * wa0.y + acc[2] * wa0.z + acc[3] * wa0.w
                + acc[4] * wa1.x + acc[5] * wa1.y + acc[6] * wa1.z + acc[7] * wa1.w
                + r[0] * wb0.x + r[1] * wb0.y + r[2] * wb0.z + r[3] * wb0.w
                + r[4] * wb1.x + r[5] * wb1.y + r[6] * wb1.z + r[7] * wb1.w;
#pragma unroll
        for (int off = 32; off; off >>= 1) v += __shfl_xor(v, off);
        p[c] = v;
    }
    if (l == 0) {
#pragma unroll
        for (int c = 0; c < C; ++c) out[(size_t)node * C + c] = p[c] + bout[c];
    }
}

extern "C" void kernel_launch(void* const* d_in, const int* in_sizes, int n_in,
                              void* d_out, int out_size, void* d_ws, size_t ws_size,
                              hipStream_t stream) {
    const float* x      = (const float*)d_in[0];
    const int*   src1   = (const int*)d_in[1];
    const int*   dst1   = (const int*)d_in[2];
    const int*   src2   = (const int*)d_in[3];
    const int*   dst2   = (const int*)d_in[4];
    const float* Wrel1  = (const float*)d_in[5];
    const float* brel1  = (const float*)d_in[6];
    const float* Wroot1 = (const float*)d_in[7];
    const float* Wrel2  = (const float*)d_in[8];
    const float* brel2  = (const float*)d_in[9];
    const float* Wroot2 = (const float*)d_in[10];
    const float* Wlin   = (const float*)d_in[11];
    const float* blin   = (const float*)d_in[12];
    const float* Whead  = (const float*)d_in[13];
    const float* bhead  = (const float*)d_in[14];
    float* out = (float*)d_out;

    const int E1 = in_sizes[1];
    const int E2 = in_sizes[3];

    // ---- workspace layout (~147 MB) ----
    char* w = (char*)d_ws;
    auto alloc = [&](size_t bytes) { char* p = w; w += (bytes + 255) & ~(size_t)255; return p; };
    unsigned short* xb    = (unsigned short*)alloc((size_t)N0 * HH * 2);
    unsigned short* agg1b = (unsigned short*)alloc((size_t)M1PAD * HH * 2);
    unsigned short* hb    = (unsigned short*)alloc((size_t)M1PAD * HH * 2);
    unsigned short* Wt    = (unsigned short*)alloc((size_t)2 * HH * HH * 2);
    float* P1    = (float*)alloc((size_t)HH * C * 4);
    float* W2aT  = (float*)alloc((size_t)HH * C * 4);
    float* W2bT  = (float*)alloc((size_t)HH * C * 4);
    float* boutp = (float*)alloc(256);
    int* ip = (int*)alloc((size_t)(2 * N1 + 2 * N2 + (N1 + 1) + (N2 + 1) + E1 + E2) * 4);
    int* cnt1  = ip;
    int* cur1  = ip + N1;
    int* cnt2  = ip + 2 * N1;
    int* cur2  = ip + 2 * N1 + N2;
    int* rs1   = ip + 2 * N1 + 2 * N2;
    int* rs2   = rs1 + N1 + 1;
    int* eidx1 = rs2 + N2 + 1;
    int* eidx2 = eidx1 + E1;

    const short* Wrel1t  = (const short*)(Wt);
    const short* Wroot1t = (const short*)(Wt + (size_t)HH * HH);

    hipMemsetAsync(ip, 0, (size_t)(2 * N1 + 2 * N2) * sizeof(int), stream);

    // ---- prep1: count + castx (grid-strided) + castw + P1 ----
    const int nbCount = (E1 + E2 + 255) / 256;
    const int nbP1    = (HH * C + 255) / 256;
    prep1_k<<<nbCount + CAST_BLOCKS + 512 + nbP1, 256, 0, stream>>>(
        dst1, dst2, cnt1, cnt2, E1, E2, x, xb, Wrel1, Wroot1, Wt,
        Wlin, Whead, P1, nbCount);

    // ---- prep2: exscans + W2aT/W2bT + bout ----
    prep2_k<<<13, 1024, 0, stream>>>(cnt1, rs1, cnt2, rs2, Wrel2, Wroot2, P1,
                                     brel2, blin, Whead, bhead, W2aT, W2bT, boutp);

    // ---- CSR fill ----
    fill_both_k<<<nbCount, 256, 0, stream>>>(src1, dst1, src2, dst2, rs1, rs2,
                                             cur1, cur2, eidx1, eidx2, E1, E2);

    // ---- layer 1 ----
    agg_bf16_k<<<(N1 + 3) / 4, 256, 0, stream>>>(xb, rs1, eidx1, agg1b, N1);
    {
        dim3 grid(HH / 128, M1PAD / 128);
        gemm_mfma_k<<<grid, 256, 0, stream>>>(
            (const short*)agg1b, Wrel1t, (const short*)xb, Wroot1t, brel1, hb, N1);
    }

    // ---- fused layer 2 + head ----
    tail_k<<<(N2 + 3) / 4, 256, 0, stream>>>(hb, rs2, eidx2, W2aT, W2bT, boutp, out);
}